// Round 6
// baseline (241.204 us; speedup 1.0000x reference)
//
#include <hip/hip_runtime.h>
#include <hip/hip_bf16.h>
#include <stdint.h>

#define DM 1024
#define DF 2048
#define NTOK 8192

typedef float f32x4 __attribute__((ext_vector_type(4)));
typedef short s16x8 __attribute__((ext_vector_type(8)));   // 8 bf16 in 4 VGPRs

__device__ __forceinline__ unsigned short f2bf(float f) {
    union { float f; unsigned int u; } v; v.f = f;
    unsigned int r = v.u + 0x7fffu + ((v.u >> 16) & 1u);   // RNE
    return (unsigned short)(r >> 16);
}

// ---------------- kernel 1: fused (a) w1/w2 -> bf16 transposed, (b) zero-out + gate + x->bf16 ----------------
// blocks [0,2048): weight transpose tiles (exact, no ghosts); [2048,4096): gating (4 tokens/block)
__global__ __launch_bounds__(256) void prep_cvt_kernel(const float* __restrict__ x,
                                                       const float* __restrict__ gw,
                                                       const float* __restrict__ gb,
                                                       const float* __restrict__ w1,
                                                       const float* __restrict__ w2,
                                                       unsigned short* __restrict__ xb,
                                                       unsigned short* __restrict__ w1t,
                                                       unsigned short* __restrict__ w2t,
                                                       float* __restrict__ out,
                                                       int* __restrict__ counts,
                                                       int* __restrict__ lists,
                                                       float* __restrict__ sls) {
    __shared__ __align__(16) char smem[32768];
    const int tid = threadIdx.x;
    if (blockIdx.x < 2048) {
        // ---- weight transpose: fp32 [k][n] -> bf16 [n][k], 64x64 tile, bf16 LDS ----
        unsigned short (*tile)[68] = (unsigned short(*)[68])smem;   // 8.7 KB
        const int tix = blockIdx.x;
        const int is2 = tix >> 10;
        const int rem = tix & 1023;
        const int e = rem >> 9;
        const int q = rem & 511;
        const int kt = is2 ? (q & 31) : (q & 15);
        const int nt = is2 ? (q >> 5) : (q >> 4);
        const int R = is2 ? DF : DM;      // src rows (k)
        const int C = is2 ? DM : DF;      // src cols (n)
        const int r0 = kt * 64, c0 = nt * 64;
        const float* src = is2 ? (w2 + (size_t)e * DF * DM) : (w1 + (size_t)e * DM * DF);
        unsigned short* dst = is2 ? (w2t + (size_t)e * DM * DF) : (w1t + (size_t)e * DM * DF);
#pragma unroll
        for (int p = 0; p < 4; ++p) {                 // load fp32, convert, stage bf16
            const int kk = (tid >> 4) + 16 * p;
            const int nq = (tid & 15) * 4;
            float4 v = *(const float4*)&src[(size_t)(r0 + kk) * C + c0 + nq];
            ushort4 o;
            o.x = f2bf(v.x); o.y = f2bf(v.y); o.z = f2bf(v.z); o.w = f2bf(v.w);
            *(ushort4*)&tile[kk][nq] = o;
        }
        __syncthreads();
#pragma unroll
        for (int p = 0; p < 4; ++p) {                 // transposed packed stores
            const int idx = tid + 256 * p;
            const int n = idx >> 4;
            const int kq = (idx & 15) * 4;
            ushort4 o;
            o.x = tile[kq + 0][n]; o.y = tile[kq + 1][n];
            o.z = tile[kq + 2][n]; o.w = tile[kq + 3][n];
            *(ushort4*)&dst[(size_t)(c0 + n) * R + r0 + kq] = o;
        }
        return;
    }
    // ---- gating + zero-out + selective x->bf16 (1 wave/token, gwT in LDS) ----
    float* gwT = (float*)smem;                      // gwT[e*1024 + d], 32 KB
    for (int i = 0; i < 32; ++i) {
        int flat = tid + 256 * i;                   // gw[flat]: d = flat>>3, e = flat&7
        gwT[(flat & 7) * 1024 + (flat >> 3)] = gw[flat];
    }
    __syncthreads();
    const int bid = blockIdx.x - 2048;
    const int wv = tid >> 6, lane = tid & 63;
    const int t = bid * 4 + wv;
    const float* xr = x + (size_t)t * DM;
    float* outr = out + (size_t)t * DM;
    float acc[8];
#pragma unroll
    for (int e = 0; e < 8; ++e) acc[e] = 0.f;
    float xs[16];
#pragma unroll
    for (int i = 0; i < 16; ++i) {
        const int d = i * 64 + lane;                // coalesced scalar loads
        xs[i] = xr[d];
#pragma unroll
        for (int e = 0; e < 8; ++e)                 // LDS bank = d%32 -> 2-way (free)
            acc[e] += xs[i] * gwT[e * 1024 + d];
    }
    const float4 z4 = make_float4(0.f, 0.f, 0.f, 0.f);
#pragma unroll
    for (int i = 0; i < 4; ++i) ((float4*)outr)[i * 64 + lane] = z4;
#pragma unroll
    for (int off = 32; off > 0; off >>= 1) {
#pragma unroll
        for (int e = 0; e < 8; ++e) acc[e] += __shfl_xor(acc[e], off, 64);
    }
    float lg[8];
#pragma unroll
    for (int e = 0; e < 8; ++e) lg[e] = acc[e] + gb[e];
    int b1i = 0; float b1v = lg[0];
#pragma unroll
    for (int e = 1; e < 8; ++e) if (lg[e] > b1v) { b1v = lg[e]; b1i = e; }
    int b2i = -1; float b2v = -3.4e38f;
#pragma unroll
    for (int e = 0; e < 8; ++e) if (e != b1i && lg[e] > b2v) { b2v = lg[e]; b2i = e; }
    const bool sel = (b1i == 0) || (b2i == 1);
    if (sel) {        // only selected tokens are ever gathered by the GEMMs
        unsigned short* xbr = xb + (size_t)t * DM;
#pragma unroll
        for (int i = 0; i < 16; ++i) xbr[i * 64 + lane] = f2bf(xs[i]);
    }
    if (lane == 0) {
        float den = 0.f;
#pragma unroll
        for (int e = 0; e < 8; ++e) den += expf(lg[e] - b1v);
        if (b1i == 0) {                       // top-1 slot matches expert 0
            float s0 = expf(lg[0] - b1v) / den;
            int p = atomicAdd(&counts[0], 1);
            lists[p] = t; sls[p] = s0;
        }
        if (b2i == 1) {                       // top-2 slot matches expert 1
            float s1 = expf(lg[1] - b1v) / den;
            int p = atomicAdd(&counts[1], 1);
            lists[NTOK + p] = t; sls[NTOK + p] = s1;
        }
    }
    if (bid == 0 && tid == 0) out[(size_t)NTOK * DM] = 0.0f;   // lbl == 0 exactly
}

// ---------------- kernels 2/3: persistent MFMA GEMM, 64x64 tile, BK=64, reg-prefetch ----------------
// Work list sized by runtime counts (zero ghost m-tiles). Grid=2048 persistent blocks;
// item wid -> (e, mt, nt[, ksp]); wid%8 keeps an n-tile's B panel on one XCD.
// K-loop: named-scalar reg prefetch (R3's arrays spilled; R5's named regs did not).
// STAGE2=false: h = gelu(Xg @ W1 + b1) -> hout (bf16 [e][NTOK][DF]); 32 n-tiles, K=1024
// STAGE2=true : out[tok] += scale*(h @ W2 + b2); 16 n-tiles, split-K=2 (KS=1024), atomicAdd
template <bool STAGE2>
__global__ __launch_bounds__(256, 4) void moe_gemm(const unsigned short* __restrict__ Aglob,
                                                   const unsigned short* __restrict__ Bglob,
                                                   const float* __restrict__ bias,
                                                   unsigned short* __restrict__ hout,
                                                   float* __restrict__ outp,
                                                   const int* __restrict__ counts,
                                                   const int* __restrict__ lists,
                                                   const float* __restrict__ sls) {
    constexpr int KTOT = STAGE2 ? DF : DM;
    constexpr int NS = 16;                         // 16 k-steps of 64 (KS = 1024 both stages)
    constexpr int RS = 80;                         // LDS row stride in bf16
    const int cnt0 = counts[0], cnt1 = counts[1];
    const int mt0 = (cnt0 + 63) >> 6, mt1 = (cnt1 + 63) >> 6;
    const int per = STAGE2 ? 32 : 32;              // items per m-tile: s1: 32 nt; s2: 16 nt * 2 ksp
    const int items0 = mt0 * per;
    const int total = items0 + mt1 * per;

    const int tid = threadIdx.x;
    const int lane = tid & 63, wv = tid >> 6;
    const int wr = wv >> 1, wc = wv & 1;           // 2x2 wave grid; wave owns 32x32
    const int lm = lane & 15, qk = lane >> 4;

    __shared__ alignas(16) unsigned short As[64 * RS];   // 10 KB
    __shared__ alignas(16) unsigned short Bs[64 * RS];   // 10 KB

    // staging map: chunk c (0..511) -> row c>>3, q = c&7; LDS slot = q ^ (row&7)
    const int rowL0 = tid >> 3,          qL0 = tid & 7;
    const int rowL1 = (tid + 256) >> 3,  qL1 = tid & 7;
    const int ofs0 = rowL0 * RS + (qL0 ^ (rowL0 & 7)) * 8;
    const int ofs1 = rowL1 * RS + (qL1 ^ (rowL1 & 7)) * 8;
    const int rA0 = wr * 32 + lm, rA1 = rA0 + 16;
    const int rB0 = wc * 32 + lm, rB1 = rB0 + 16;

#pragma unroll 1
    for (int wid = blockIdx.x; wid < total; wid += gridDim.x) {
        const int e   = (wid < items0) ? 0 : 1;
        const int rem = (wid < items0) ? wid : wid - items0;
        const int Ne  = e ? cnt1 : cnt0;
        const int mt  = rem >> 5;
        const int nt  = STAGE2 ? ((rem >> 1) & 15) : (rem & 31);
        const int ksp = STAGE2 ? (rem & 1) : 0;
        const int m0 = mt * 64, n0 = nt * 64, k0 = ksp * 1024;

        const int* list = lists + e * NTOK;
        const unsigned short* Ae = STAGE2 ? (Aglob + (size_t)e * NTOK * DF) : Aglob;
        const unsigned short* Be = Bglob + (size_t)e * DM * DF;

        int rgA0 = m0 + rowL0; if (rgA0 >= Ne) rgA0 = m0;    // clamp: epilogue-guarded
        int rgA1 = m0 + rowL1; if (rgA1 >= Ne) rgA1 = m0;
        const size_t arow0 = STAGE2 ? (size_t)rgA0 * KTOT : (size_t)list[rgA0] * KTOT;
        const size_t arow1 = STAGE2 ? (size_t)rgA1 * KTOT : (size_t)list[rgA1] * KTOT;
        const unsigned short* sa0 = Ae + arow0 + k0 + qL0 * 8;
        const unsigned short* sa1 = Ae + arow1 + k0 + qL1 * 8;
        const unsigned short* sb0 = Be + (size_t)(n0 + rowL0) * KTOT + k0 + qL0 * 8;
        const unsigned short* sb1 = Be + (size_t)(n0 + rowL1) * KTOT + k0 + qL1 * 8;

        f32x4 acc00 = {0.f,0.f,0.f,0.f}, acc01 = acc00, acc10 = acc00, acc11 = acc00;

        __syncthreads();                             // LDS safe to overwrite (prev item done)
        uint4 pa0 = *(const uint4*)sa0; sa0 += 64;
        uint4 pa1 = *(const uint4*)sa1; sa1 += 64;
        uint4 pb0 = *(const uint4*)sb0; sb0 += 64;
        uint4 pb1 = *(const uint4*)sb1; sb1 += 64;
        *(uint4*)&As[ofs0] = pa0;  *(uint4*)&As[ofs1] = pa1;
        *(uint4*)&Bs[ofs0] = pb0;  *(uint4*)&Bs[ofs1] = pb1;
        __syncthreads();

#pragma unroll 1
        for (int s = 0; s < NS; ++s) {
            const bool pre = (s + 1 < NS);
            if (pre) {                               // prefetch tile s+1 (in flight during MFMA)
                pa0 = *(const uint4*)sa0; sa0 += 64;
                pa1 = *(const uint4*)sa1; sa1 += 64;
                pb0 = *(const uint4*)sb0; sb0 += 64;
                pb1 = *(const uint4*)sb1; sb1 += 64;
            }
#pragma unroll
            for (int h = 0; h < 2; ++h) {            // two 16x16x32 k-slices of BK=64
                const int c = h * 4 + qk;
                s16x8 af0 = *(const s16x8*)&As[rA0 * RS + ((c ^ (rA0 & 7)) * 8)];
                s16x8 af1 = *(const s16x8*)&As[rA1 * RS + ((c ^ (rA1 & 7)) * 8)];
                s16x8 bf0 = *(const s16x8*)&Bs[rB0 * RS + ((c ^ (rB0 & 7)) * 8)];
                s16x8 bf1 = *(const s16x8*)&Bs[rB1 * RS + ((c ^ (rB1 & 7)) * 8)];
                acc00 = __builtin_amdgcn_mfma_f32_16x16x32_bf16(af0, bf0, acc00, 0, 0, 0);
                acc01 = __builtin_amdgcn_mfma_f32_16x16x32_bf16(af0, bf1, acc01, 0, 0, 0);
                acc10 = __builtin_amdgcn_mfma_f32_16x16x32_bf16(af1, bf0, acc10, 0, 0, 0);
                acc11 = __builtin_amdgcn_mfma_f32_16x16x32_bf16(af1, bf1, acc11, 0, 0, 0);
            }
            if (pre) {
                __syncthreads();                     // all waves done reading LDS
                *(uint4*)&As[ofs0] = pa0;  *(uint4*)&As[ofs1] = pa1;
                *(uint4*)&Bs[ofs0] = pb0;  *(uint4*)&Bs[ofs1] = pb1;
                __syncthreads();                     // staging visible
            }
        }

        // epilogue: C/D layout col = lane&15, row = (lane>>4)*4 + reg
        f32x4 accs[2][2] = {{acc00, acc01}, {acc10, acc11}};
        if (!STAGE2) {
            const float* be = bias + e * DF;
            unsigned short* he = hout + (size_t)e * NTOK * DF;
#pragma unroll
            for (int am = 0; am < 2; ++am) {
#pragma unroll
                for (int bn = 0; bn < 2; ++bn) {
                    int ng = n0 + wc * 32 + bn * 16 + lm;
                    float bb = be[ng];
                    f32x4 v = accs[am][bn];
#pragma unroll
                    for (int r = 0; r < 4; ++r) {
                        int ml = wr * 32 + am * 16 + qk * 4 + r;
                        int rg = m0 + ml;
                        if (rg < Ne) {
                            float tpre = v[r] + bb;
                            float gl = 0.5f * tpre * (1.0f + erff(tpre * 0.70710678118654752f));
                            he[(size_t)rg * DF + ng] = f2bf(gl);
                        }
                    }
                }
            }
        } else {
            const float* be = bias + e * DM;
            const float* sl = sls + e * NTOK;
#pragma unroll
            for (int am = 0; am < 2; ++am) {
#pragma unroll
                for (int bn = 0; bn < 2; ++bn) {
                    int ng = n0 + wc * 32 + bn * 16 + lm;
                    float bb = (ksp == 0) ? be[ng] : 0.0f;   // bias added by split 0 only
                    f32x4 v = accs[am][bn];
#pragma unroll
                    for (int r = 0; r < 4; ++r) {
                        int ml = wr * 32 + am * 16 + qk * 4 + r;
                        int rg = m0 + ml;
                        if (rg < Ne) {
                            int tok = list[rg];
                            float s = sl[rg];
                            atomicAdd(&outp[(size_t)tok * DM + ng], s * (v[r] + bb));
                        }
                    }
                }
            }
        }
    }
}

extern "C" void kernel_launch(void* const* d_in, const int* in_sizes, int n_in,
                              void* d_out, int out_size, void* d_ws, size_t ws_size,
                              hipStream_t stream) {
    const float* x  = (const float*)d_in[0];
    const float* gw = (const float*)d_in[1];
    const float* gb = (const float*)d_in[2];
    const float* w1 = (const float*)d_in[3];
    const float* b1 = (const float*)d_in[4];
    const float* w2 = (const float*)d_in[5];
    const float* b2 = (const float*)d_in[6];
    float* out = (float*)d_out;
    char* ws = (char*)d_ws;

    // ws layout (bytes): [0] counts, [1024] lists[2][8192], [66560] sls[2][8192],
    // [262144] xb bf16[8192*1024], [+16MiB] w1t bf16[2][2048][1024],
    // [+8MiB] w2t bf16[2][1024][2048], [+8MiB] h bf16[2][8192][2048].  Total ~96.3 MB.
    int*            counts = (int*)(ws + 0);
    int*            lists  = (int*)(ws + 1024);
    float*          sls    = (float*)(ws + 1024 + 65536);
    unsigned short* xb     = (unsigned short*)(ws + 262144);
    unsigned short* w1t    = (unsigned short*)(ws + 262144 + 16777216);
    unsigned short* w2t    = (unsigned short*)(ws + 262144 + 16777216 + 8388608);
    unsigned short* hbuf   = (unsigned short*)(ws + 262144 + 16777216 + 16777216);

    hipMemsetAsync(counts, 0, 8, stream);
    prep_cvt_kernel<<<4096, 256, 0, stream>>>(x, gw, gb, w1, w2, xb, w1t, w2t,
                                              out, counts, lists, sls);
    moe_gemm<false><<<2048, 256, 0, stream>>>(xb, w1t, b1, hbuf, nullptr, counts, lists, sls);
    moe_gemm<true><<<2048, 256, 0, stream>>>(hbuf, w2t, b2, nullptr, out, counts, lists, sls);
}